// Round 1
// baseline (1373.628 us; speedup 1.0000x reference)
//
#include <hip/hip_runtime.h>
#include <math.h>

// Model dims
#define VOCAB 10000
#define DM 256
#define NL 6
#define DI 512
#define DS_ 16
#define DTR 16
#define BB 32
#define SL 64
#define M_TOK 2048   // BB*SL effective rows (neuron axis collapsed: all neurons identical)

__device__ __forceinline__ float sigm(float x){ return 1.f/(1.f+__expf(-x)); }

// ---------------- embedding gather ----------------
__global__ __launch_bounds__(256) void embed_kernel(const int* __restrict__ tok,
    const float* __restrict__ emb, float* __restrict__ x){
  int row = blockIdx.x;
  int c = threadIdx.x;
  x[(size_t)row*DM + c] = emb[(size_t)tok[row]*DM + c];
}

// ---------------- layernorm: one wave (64 lanes) per row of 256 ----------------
__global__ __launch_bounds__(64) void ln_kernel(const float* __restrict__ x,
    const float* __restrict__ g, const float* __restrict__ b, float* __restrict__ o){
  int row = blockIdx.x;
  int lane = threadIdx.x;
  const float4 v = *(const float4*)(x + (size_t)row*DM + lane*4);
  float s = v.x+v.y+v.z+v.w;
  #pragma unroll
  for (int off=32; off; off>>=1) s += __shfl_xor(s, off, 64);
  float m = s * (1.f/DM);
  float d0=v.x-m, d1=v.y-m, d2=v.z-m, d3=v.w-m;
  float q = d0*d0+d1*d1+d2*d2+d3*d3;
  #pragma unroll
  for (int off=32; off; off>>=1) q += __shfl_xor(q, off, 64);
  float r = rsqrtf(q*(1.f/DM) + 1e-5f);
  const float4 gv = *(const float4*)(g + lane*4);
  const float4 bv = *(const float4*)(b + lane*4);
  float4 ov;
  ov.x = d0*r*gv.x + bv.x;
  ov.y = d1*r*gv.y + bv.y;
  ov.z = d2*r*gv.z + bv.z;
  ov.w = d3*r*gv.w + bv.w;
  *(float4*)(o + (size_t)row*DM + lane*4) = ov;
}

// ---------------- generic fp32 NT GEMM: D[M,N] = A[M,K] @ W[N,K]^T ----------------
// MODE: 0 = plain, 1 = softplus(acc+bias), 2 = res + acc (+bias)
// BIAS: add bias[col]
template<int MODE, int BIAS>
__global__ __launch_bounds__(256) void gemm_nt(const float* __restrict__ A, int lda,
    const float* __restrict__ W,
    const float* __restrict__ bias,
    const float* __restrict__ res,
    float* __restrict__ D,
    int N, int K){
  constexpr int BM=64, BN=64, BK=16;
  __shared__ float As[BK][BM+4];
  __shared__ float Ws[BK][BN+4];
  const int tid = threadIdx.x;
  const int bm = blockIdx.x * BM;
  const int bn = blockIdx.y * BN;
  const int tm = (tid>>4)<<2;   // 0..60
  const int tn = (tid&15)<<2;   // 0..60
  const int lr = tid>>2;        // 0..63
  const int lk = (tid&3)<<2;    // 0,4,8,12
  const int wrow = bn + lr;
  float acc[4][4] = {};
  for (int k0=0; k0<K; k0+=BK){
    float4 av = *(const float4*)(A + (size_t)(bm+lr)*lda + k0 + lk);
    As[lk+0][lr]=av.x; As[lk+1][lr]=av.y; As[lk+2][lr]=av.z; As[lk+3][lr]=av.w;
    float4 wv = make_float4(0.f,0.f,0.f,0.f);
    if (wrow < N) wv = *(const float4*)(W + (size_t)wrow*K + k0 + lk);
    Ws[lk+0][lr]=wv.x; Ws[lk+1][lr]=wv.y; Ws[lk+2][lr]=wv.z; Ws[lk+3][lr]=wv.w;
    __syncthreads();
    #pragma unroll
    for (int k=0;k<BK;k++){
      float4 a = *(const float4*)&As[k][tm];
      float4 w = *(const float4*)&Ws[k][tn];
      float ar[4] = {a.x,a.y,a.z,a.w};
      float wr[4] = {w.x,w.y,w.z,w.w};
      #pragma unroll
      for (int i=0;i<4;i++)
        #pragma unroll
        for (int j=0;j<4;j++)
          acc[i][j] = fmaf(ar[i], wr[j], acc[i][j]);
    }
    __syncthreads();
  }
  #pragma unroll
  for (int i=0;i<4;i++){
    const int row = bm + tm + i;
    #pragma unroll
    for (int j=0;j<4;j++){
      const int col = bn + tn + j;
      if (col < N){
        float v = acc[i][j];
        if (BIAS) v += bias[col];
        if (MODE==1) v = (v > 20.f) ? v : log1pf(__expf(v));
        if (MODE==2) v += res[(size_t)row*N + col];
        D[(size_t)row*N + col] = v;
      }
    }
  }
}

// ---------------- depthwise causal conv (DC=4) + SiLU ----------------
__global__ __launch_bounds__(256) void conv_silu_kernel(const float* __restrict__ xz,
    const float* __restrict__ cw, const float* __restrict__ cb, float* __restrict__ u){
  int idx = blockIdx.x*256 + threadIdx.x;   // over 2048*512
  int d = idx & (DI-1);
  int row = idx >> 9;     // b*SL + t
  int t = row & (SL-1);
  const float4 w = *(const float4*)(cw + d*4);
  float acc = cb[d];
  const float* base = xz + (size_t)row*(2*DI) + d;
  acc = fmaf(base[0], w.w, acc);
  if (t>=1) acc = fmaf(base[-(2*DI)],   w.z, acc);
  if (t>=2) acc = fmaf(base[-2*(2*DI)], w.y, acc);
  if (t>=3) acc = fmaf(base[-3*(2*DI)], w.x, acc);
  u[idx] = acc * sigm(acc);
}

// ---------------- selective scan: thread = (b, d) channel, serial over t ----------------
__global__ __launch_bounds__(128) void scan_kernel(const float* __restrict__ dt,
    const float* __restrict__ u, const float* __restrict__ xdbl,
    const float* __restrict__ xz, const float* __restrict__ alog,
    const float* __restrict__ Dp, float* __restrict__ ym){
  const int b = blockIdx.x;
  const int d = blockIdx.y*128 + threadIdx.x;
  float A[DS_], h[DS_];
  #pragma unroll
  for (int s=0;s<DS_;s++){ A[s] = -__expf(alog[(size_t)d*DS_+s]); h[s]=0.f; }
  const float Dv = Dp[d];
  for (int t=0;t<SL;t++){
    const int row = b*SL + t;
    const float dtv = dt[(size_t)row*DI + d];
    const float uv  = u[(size_t)row*DI + d];
    const float du  = dtv*uv;
    const float* xb = xdbl + (size_t)row*48;
    float acc = 0.f;
    #pragma unroll
    for (int s=0;s<DS_;s++){
      float dA = __expf(dtv*A[s]);
      h[s] = fmaf(h[s], dA, du*xb[16+s]);
      acc = fmaf(h[s], xb[32+s], acc);
    }
    const float zv = xz[(size_t)row*(2*DI) + DI + d];
    const float sz = zv * sigm(zv);
    ym[(size_t)row*DI + d] = (acc + uv*Dv)*sz;
  }
}

extern "C" void kernel_launch(void* const* d_in, const int* in_sizes, int n_in,
                              void* d_out, int out_size, void* d_ws, size_t ws_size,
                              hipStream_t stream){
  const int*   tokens = (const int*)d_in[0];
  const float* emb    = (const float*)d_in[1];
  const float* head_b = (const float*)d_in[2];
  const float* in_w   = (const float*)d_in[3];
  const float* conv_w = (const float*)d_in[4];
  const float* conv_b = (const float*)d_in[5];
  const float* xp_w   = (const float*)d_in[6];
  const float* dt_w   = (const float*)d_in[7];
  const float* dt_b   = (const float*)d_in[8];
  const float* a_log  = (const float*)d_in[9];
  const float* d_par  = (const float*)d_in[10];
  const float* out_w  = (const float*)d_in[11];
  const float* ai_w   = (const float*)d_in[12];
  const float* ai_b   = (const float*)d_in[13];
  const float* ao_w   = (const float*)d_in[14];
  const float* ao_b   = (const float*)d_in[15];
  const float* ln1g   = (const float*)d_in[16];
  const float* ln1b   = (const float*)d_in[17];
  const float* ln2g   = (const float*)d_in[18];
  const float* ln2b   = (const float*)d_in[19];
  const float* lnfg   = (const float*)d_in[20];
  const float* lnfb   = (const float*)d_in[21];
  float* out = (float*)d_out;

  float* ws = (float*)d_ws;
  float* x    = ws;                  // 2048*256
  float* xn   = x    + M_TOK*DM;     // 2048*256
  float* xz   = xn   + M_TOK*DM;     // 2048*1024
  float* u    = xz   + M_TOK*2*DI;   // 2048*512
  float* xdbl = u    + M_TOK*DI;     // 2048*48
  float* dtb  = xdbl + M_TOK*48;     // 2048*512
  float* ym   = dtb  + M_TOK*DI;     // 2048*512 (also reused as attn V buffer)

  embed_kernel<<<M_TOK,256,0,stream>>>(tokens, emb, x);
  for (int l=0;l<NL;l++){
    // --- mamba branch ---
    ln_kernel<<<M_TOK,64,0,stream>>>(x, ln1g+l*DM, ln1b+l*DM, xn);
    gemm_nt<0,0><<<dim3(M_TOK/64,(2*DI)/64),256,0,stream>>>(
        xn, DM, in_w + (size_t)l*2*DI*DM, nullptr, nullptr, xz, 2*DI, DM);
    conv_silu_kernel<<<(M_TOK*DI)/256,256,0,stream>>>(
        xz, conv_w + (size_t)l*DI*4, conv_b + (size_t)l*DI, u);
    gemm_nt<0,0><<<dim3(M_TOK/64,1),256,0,stream>>>(
        u, DI, xp_w + (size_t)l*(DTR+2*DS_)*DI, nullptr, nullptr, xdbl, DTR+2*DS_, DI);
    gemm_nt<1,1><<<dim3(M_TOK/64,DI/64),256,0,stream>>>(
        xdbl, DTR+2*DS_, dt_w + (size_t)l*DI*DTR, dt_b + (size_t)l*DI, nullptr, dtb, DI, DTR);
    scan_kernel<<<dim3(BB,DI/128),128,0,stream>>>(
        dtb, u, xdbl, xz, a_log + (size_t)l*DI*DS_, d_par + (size_t)l*DI, ym);
    gemm_nt<2,0><<<dim3(M_TOK/64,DM/64),256,0,stream>>>(
        ym, DI, out_w + (size_t)l*DM*DI, nullptr, x, x, DM, DI);
    // --- attention branch (collapsed: identical neurons -> uniform softmax -> out = V) ---
    ln_kernel<<<M_TOK,64,0,stream>>>(x, ln2g+l*DM, ln2b+l*DM, xn);
    gemm_nt<0,1><<<dim3(M_TOK/64,DM/64),256,0,stream>>>(
        xn, DM, ai_w + (size_t)l*3*DM*DM + (size_t)2*DM*DM, ai_b + (size_t)l*3*DM + 2*DM,
        nullptr, ym, DM, DM);
    gemm_nt<2,1><<<dim3(M_TOK/64,DM/64),256,0,stream>>>(
        ym, DM, ao_w + (size_t)l*DM*DM, ao_b + (size_t)l*DM, x, x, DM, DM);
  }
  // --- final LN + tied head ---
  ln_kernel<<<M_TOK,64,0,stream>>>(x, lnfg, lnfb, xn);
  gemm_nt<0,1><<<dim3(M_TOK/64,(VOCAB+63)/64),256,0,stream>>>(
      xn, DM, emb, head_b, nullptr, out, VOCAB, DM);
}

// Round 2
// 733.596 us; speedup vs baseline: 1.8725x; 1.8725x over previous
//
#include <hip/hip_runtime.h>
#include <math.h>

// Model dims
#define VOCAB 10000
#define DM 256
#define NL 6
#define DI 512
#define DS_ 16
#define DTR 16
#define BB 32
#define SL 64
#define M_TOK 2048   // BB*SL effective rows (neuron axis collapsed: all neurons identical)

typedef __attribute__((ext_vector_type(8))) short short8;
typedef __attribute__((ext_vector_type(4))) float f32x4;

__device__ __forceinline__ float sigm(float x){ return 1.f/(1.f+__expf(-x)); }

// round-to-nearest-even fp32 -> bf16 (as ushort)
__device__ __forceinline__ ushort f2bf(float x){
  unsigned u = __float_as_uint(x);
  u += 0x7fffu + ((u>>16)&1u);
  return (ushort)(u>>16);
}

// ---------------- bulk fp32 -> bf16 weight conversion (segmented, one launch) ----------------
struct CvtSeg { const float* src; ushort* dst; int nvec; };
struct CvtArgs { CvtSeg seg[6]; int cum[7]; };
__global__ __launch_bounds__(256) void convert_kernel(CvtArgs a){
  int b = blockIdx.x;
  int s = 0;
  while (b >= a.cum[s+1]) s++;
  int vidx = (b - a.cum[s])*256 + threadIdx.x;
  if (vidx < a.seg[s].nvec){
    float4 v = ((const float4*)a.seg[s].src)[vidx];
    ushort4 o; o.x=f2bf(v.x); o.y=f2bf(v.y); o.z=f2bf(v.z); o.w=f2bf(v.w);
    ((ushort4*)a.seg[s].dst)[vidx] = o;
  }
}

// ---------------- embedding gather ----------------
__global__ __launch_bounds__(256) void embed_kernel(const int* __restrict__ tok,
    const float* __restrict__ emb, float* __restrict__ x){
  int row = blockIdx.x;
  int c = threadIdx.x;
  x[(size_t)row*DM + c] = emb[(size_t)tok[row]*DM + c];
}

// ---------------- layernorm: one wave per row of 256; writes bf16 ----------------
__global__ __launch_bounds__(64) void ln_kernel(const float* __restrict__ x,
    const float* __restrict__ g, const float* __restrict__ b, ushort* __restrict__ o){
  int row = blockIdx.x;
  int lane = threadIdx.x;
  const float4 v = *(const float4*)(x + (size_t)row*DM + lane*4);
  float s = v.x+v.y+v.z+v.w;
  #pragma unroll
  for (int off=32; off; off>>=1) s += __shfl_xor(s, off, 64);
  float m = s * (1.f/DM);
  float d0=v.x-m, d1=v.y-m, d2=v.z-m, d3=v.w-m;
  float q = d0*d0+d1*d1+d2*d2+d3*d3;
  #pragma unroll
  for (int off=32; off; off>>=1) q += __shfl_xor(q, off, 64);
  float r = rsqrtf(q*(1.f/DM) + 1e-5f);
  const float4 gv = *(const float4*)(g + lane*4);
  const float4 bv = *(const float4*)(b + lane*4);
  ushort4 ov;
  ov.x = f2bf(d0*r*gv.x + bv.x);
  ov.y = f2bf(d1*r*gv.y + bv.y);
  ov.z = f2bf(d2*r*gv.z + bv.z);
  ov.w = f2bf(d3*r*gv.w + bv.w);
  *(ushort4*)(o + (size_t)row*DM + lane*4) = ov;
}

// ---------------- MFMA bf16 NT GEMM: D[M,N] = A[M,K] @ W[N,K]^T  (fp32 accum) --------------
// 64x64 tile, 4 waves, BK=32. LDS stride 40 ushort (80B) -> conflict-free ds_read_b128.
template<bool BIAS, bool RES, bool OUTF32, bool OUTBF>
__global__ __launch_bounds__(256) void mgemm(
    const ushort* __restrict__ A, int lda,
    const ushort* __restrict__ W,
    const float* __restrict__ bias,
    const float* __restrict__ res,
    float* __restrict__ Df, ushort* __restrict__ Db,
    int N, int K)
{
  __shared__ ushort As[64*40];
  __shared__ ushort Bs[64*40];
  const int tid = threadIdx.x;
  const int bm = blockIdx.x*64, bn = blockIdx.y*64;
  const int r = tid>>2, c = tid&3;          // staging: row 0..63, 8-elem chunk 0..3
  const int lane = tid & 63, wave = tid>>6;
  const int wm = wave>>1, wn = wave&1;      // wave's 32x32 quadrant
  const int lr = lane&15, lk = (lane>>4)*8;
  f32x4 acc[2][2] = {};
  for (int k0=0; k0<K; k0+=32){
    uint4 av = make_uint4(0,0,0,0), wv = make_uint4(0,0,0,0);
    const bool kok = (k0 + c*8) < K;
    if (kok)
      av = *(const uint4*)(A + (size_t)(bm+r)*lda + k0 + c*8);
    const int n = bn + r;
    if (kok && n < N)
      wv = *(const uint4*)(W + (size_t)n*K + k0 + c*8);
    __syncthreads();
    *(uint4*)&As[r*40 + c*8] = av;
    *(uint4*)&Bs[r*40 + c*8] = wv;
    __syncthreads();
    short8 a0 = *(const short8*)&As[(wm*32 +  0 + lr)*40 + lk];
    short8 a1 = *(const short8*)&As[(wm*32 + 16 + lr)*40 + lk];
    short8 b0 = *(const short8*)&Bs[(wn*32 +  0 + lr)*40 + lk];
    short8 b1 = *(const short8*)&Bs[(wn*32 + 16 + lr)*40 + lk];
    acc[0][0] = __builtin_amdgcn_mfma_f32_16x16x32_bf16(a0,b0,acc[0][0],0,0,0);
    acc[0][1] = __builtin_amdgcn_mfma_f32_16x16x32_bf16(a0,b1,acc[0][1],0,0,0);
    acc[1][0] = __builtin_amdgcn_mfma_f32_16x16x32_bf16(a1,b0,acc[1][0],0,0,0);
    acc[1][1] = __builtin_amdgcn_mfma_f32_16x16x32_bf16(a1,b1,acc[1][1],0,0,0);
  }
  #pragma unroll
  for (int i=0;i<2;i++){
    #pragma unroll
    for (int j=0;j<2;j++){
      #pragma unroll
      for (int q=0;q<4;q++){
        const int row = bm + wm*32 + i*16 + (lane>>4)*4 + q;
        const int col = bn + wn*32 + j*16 + lr;
        if (col < N){
          float v = acc[i][j][q];
          if (BIAS) v += bias[col];
          if (RES)  v += res[(size_t)row*N + col];
          if (OUTF32) Df[(size_t)row*N + col] = v;
          if (OUTBF)  Db[(size_t)row*N + col] = f2bf(v);
        }
      }
    }
  }
}

// ---------------- depthwise causal conv (DC=4) + SiLU; writes fp32 + bf16 ----------------
__global__ __launch_bounds__(256) void conv_silu_kernel(const float* __restrict__ xz,
    const float* __restrict__ cw, const float* __restrict__ cb,
    float* __restrict__ u, ushort* __restrict__ ub){
  int idx = blockIdx.x*256 + threadIdx.x;   // over 2048*512
  int d = idx & (DI-1);
  int row = idx >> 9;     // b*SL + t
  int t = row & (SL-1);
  const float4 w = *(const float4*)(cw + d*4);
  float acc = cb[d];
  const float* base = xz + (size_t)row*(2*DI) + d;
  acc = fmaf(base[0], w.w, acc);
  if (t>=1) acc = fmaf(base[-(2*DI)],   w.z, acc);
  if (t>=2) acc = fmaf(base[-2*(2*DI)], w.y, acc);
  if (t>=3) acc = fmaf(base[-3*(2*DI)], w.x, acc);
  float v = acc * sigm(acc);
  u[idx] = v;
  ub[idx] = f2bf(v);
}

// ---------------- selective scan with fused dt-projection + softplus + gate ----------------
// grid (BB, DI/128), 128 threads; xdbl tile for the sequence staged in LDS.
__global__ __launch_bounds__(128) void scan_kernel(
    const float* __restrict__ xdbl,  // [2048][48]
    const float* __restrict__ u,     // [2048][512]
    const float* __restrict__ xz,    // [2048][1024] (z at +512)
    const float* __restrict__ dtw,   // [512][16]
    const float* __restrict__ dtb,   // [512]
    const float* __restrict__ alog,  // [512][16]
    const float* __restrict__ Dp,    // [512]
    ushort* __restrict__ ymb)        // [2048][512] bf16
{
  __shared__ float xs[SL][48];
  const int b = blockIdx.x;
  const int d = blockIdx.y*128 + threadIdx.x;
  for (int i = threadIdx.x; i < SL*48/4; i += 128)
    ((float4*)&xs[0][0])[i] = ((const float4*)(xdbl + (size_t)b*SL*48))[i];
  float wdt[DS_], A[DS_], h[DS_];
  #pragma unroll
  for (int s=0;s<DS_;s++){
    wdt[s] = dtw[(size_t)d*DS_+s];
    A[s] = -__expf(alog[(size_t)d*DS_+s]);
    h[s] = 0.f;
  }
  const float bdt = dtb[d], Dv = Dp[d];
  __syncthreads();
  for (int t=0;t<SL;t++){
    const int row = b*SL + t;
    const float uv = u[(size_t)row*DI + d];
    const float zv = xz[(size_t)row*(2*DI) + DI + d];
    float dtv = bdt;
    #pragma unroll
    for (int s=0;s<DS_;s++) dtv = fmaf(xs[t][s], wdt[s], dtv);
    dtv = (dtv > 20.f) ? dtv : log1pf(__expf(dtv));
    const float du = dtv*uv;
    float acc = 0.f;
    #pragma unroll
    for (int s=0;s<DS_;s++){
      float dA = __expf(dtv*A[s]);
      h[s] = fmaf(h[s], dA, du*xs[t][16+s]);
      acc = fmaf(h[s], xs[t][32+s], acc);
    }
    const float sz = zv * sigm(zv);
    ymb[(size_t)row*DI + d] = f2bf((acc + uv*Dv)*sz);
  }
}

extern "C" void kernel_launch(void* const* d_in, const int* in_sizes, int n_in,
                              void* d_out, int out_size, void* d_ws, size_t ws_size,
                              hipStream_t stream){
  const int*   tokens = (const int*)d_in[0];
  const float* emb    = (const float*)d_in[1];
  const float* head_b = (const float*)d_in[2];
  const float* in_w   = (const float*)d_in[3];
  const float* conv_w = (const float*)d_in[4];
  const float* conv_b = (const float*)d_in[5];
  const float* xp_w   = (const float*)d_in[6];
  const float* dt_w   = (const float*)d_in[7];
  const float* dt_b   = (const float*)d_in[8];
  const float* a_log  = (const float*)d_in[9];
  const float* d_par  = (const float*)d_in[10];
  const float* out_w  = (const float*)d_in[11];
  const float* ai_w   = (const float*)d_in[12];
  const float* ai_b   = (const float*)d_in[13];
  const float* ao_w   = (const float*)d_in[14];
  const float* ao_b   = (const float*)d_in[15];
  const float* ln1g   = (const float*)d_in[16];
  const float* ln1b   = (const float*)d_in[17];
  const float* ln2g   = (const float*)d_in[18];
  const float* ln2b   = (const float*)d_in[19];
  const float* lnfg   = (const float*)d_in[20];
  const float* lnfb   = (const float*)d_in[21];
  float* out = (float*)d_out;

  // ---- workspace layout ----
  float* fp = (float*)d_ws;
  float* x    = fp;  fp += M_TOK*DM;        // 524288
  float* xz   = fp;  fp += M_TOK*2*DI;      // 2097152
  float* u    = fp;  fp += M_TOK*DI;        // 1048576
  float* xdbl = fp;  fp += M_TOK*48;        // 98304
  ushort* up = (ushort*)fp;
  ushort* xn_bf  = up;  up += M_TOK*DM;     // 524288
  ushort* u_bf   = up;  up += M_TOK*DI;     // 1048576
  ushort* ym_bf  = up;  up += M_TOK*DI;     // 1048576
  ushort* v_bf   = up;  up += M_TOK*DM;     // 524288
  ushort* emb_bf = up;  up += VOCAB*DM;     // 2560000
  ushort* inw_bf = up;  up += NL*2*DI*DM;   // 1572864
  ushort* outw_bf= up;  up += NL*DM*DI;     // 786432
  ushort* aiw_bf = up;  up += NL*3*DM*DM;   // 1179648
  ushort* aow_bf = up;  up += NL*DM*DM;     // 393216
  ushort* xpw_bf = up;  up += NL*48*DI;     // 147456

  // ---- weight conversion (one launch) ----
  CvtArgs ca;
  const float* srcs[6] = {emb, in_w, out_w, ai_w, ao_w, xp_w};
  ushort* dsts[6] = {emb_bf, inw_bf, outw_bf, aiw_bf, aow_bf, xpw_bf};
  const int cnts[6] = {VOCAB*DM, NL*2*DI*DM, NL*DM*DI, NL*3*DM*DM, NL*DM*DM, NL*48*DI};
  int cum = 0;
  ca.cum[0] = 0;
  for (int i=0;i<6;i++){
    ca.seg[i].src = srcs[i]; ca.seg[i].dst = dsts[i]; ca.seg[i].nvec = cnts[i]/4;
    cum += (ca.seg[i].nvec + 255)/256;
    ca.cum[i+1] = cum;
  }
  convert_kernel<<<cum,256,0,stream>>>(ca);

  embed_kernel<<<M_TOK,256,0,stream>>>(tokens, emb, x);
  for (int l=0;l<NL;l++){
    // --- mamba branch ---
    ln_kernel<<<M_TOK,64,0,stream>>>(x, ln1g+l*DM, ln1b+l*DM, xn_bf);
    mgemm<false,false,true,false><<<dim3(M_TOK/64,(2*DI)/64),256,0,stream>>>(
        xn_bf, DM, inw_bf + (size_t)l*2*DI*DM, nullptr, nullptr, xz, nullptr, 2*DI, DM);
    conv_silu_kernel<<<(M_TOK*DI)/256,256,0,stream>>>(
        xz, conv_w + (size_t)l*DI*4, conv_b + (size_t)l*DI, u, u_bf);
    mgemm<false,false,true,false><<<dim3(M_TOK/64,1),256,0,stream>>>(
        u_bf, DI, xpw_bf + (size_t)l*48*DI, nullptr, nullptr, xdbl, nullptr, 48, DI);
    scan_kernel<<<dim3(BB,DI/128),128,0,stream>>>(
        xdbl, u, xz, dt_w + (size_t)l*DI*DTR, dt_b + (size_t)l*DI,
        a_log + (size_t)l*DI*DS_, d_par + (size_t)l*DI, ym_bf);
    mgemm<false,true,true,false><<<dim3(M_TOK/64,DM/64),256,0,stream>>>(
        ym_bf, DI, outw_bf + (size_t)l*DM*DI, nullptr, x, x, nullptr, DM, DI);
    // --- attention branch (collapsed: identical neurons -> out = V path only) ---
    ln_kernel<<<M_TOK,64,0,stream>>>(x, ln2g+l*DM, ln2b+l*DM, xn_bf);
    mgemm<true,false,false,true><<<dim3(M_TOK/64,DM/64),256,0,stream>>>(
        xn_bf, DM, aiw_bf + (size_t)l*3*DM*DM + (size_t)2*DM*DM,
        ai_b + (size_t)l*3*DM + 2*DM, nullptr, nullptr, v_bf, DM, DM);
    mgemm<true,true,true,false><<<dim3(M_TOK/64,DM/64),256,0,stream>>>(
        v_bf, DM, aow_bf + (size_t)l*DM*DM, ao_b + (size_t)l*DM, x, x, nullptr, DM, DM);
  }
  // --- final LN + tied head ---
  ln_kernel<<<M_TOK,64,0,stream>>>(x, lnfg, lnfb, xn_bf);
  mgemm<true,false,true,false><<<dim3(M_TOK/64,(VOCAB+63)/64),256,0,stream>>>(
      xn_bf, DM, emb_bf, head_b, nullptr, out, nullptr, VOCAB, DM);
}

// Round 5
// 722.478 us; speedup vs baseline: 1.9013x; 1.0154x over previous
//
#include <hip/hip_runtime.h>
#include <math.h>

#define VOCAB 10000
#define DM 256
#define NL 6
#define DI 512
#define DS_ 16
#define DTR 16
#define BB 32
#define SL 64
#define M_TOK 2048   // BB*SL effective rows (neuron axis collapsed: identical neurons)

typedef __attribute__((ext_vector_type(8))) short short8;
typedef __attribute__((ext_vector_type(4))) float f32x4;

__device__ __forceinline__ float sigm(float x){ return 1.f/(1.f+__expf(-x)); }
__device__ __forceinline__ ushort f2bf(float x){
  unsigned u = __float_as_uint(x);
  u += 0x7fffu + ((u>>16)&1u);
  return (ushort)(u>>16);
}
__device__ __forceinline__ float bf2f(ushort h){ return __uint_as_float(((unsigned)h)<<16); }

// ---------------- bulk fp32 -> bf16 weight conversion (5 segments, one launch) -----------
struct CvtArgs { const float* src[5]; ushort* dst[5]; int nvec[5]; int cum[6]; };
__global__ __launch_bounds__(256) void convert_kernel(CvtArgs a){
  int b = blockIdx.x, s = 0;
  while (b >= a.cum[s+1]) s++;
  int v = (b - a.cum[s])*256 + threadIdx.x;
  if (v < a.nvec[s]){
    float4 x = ((const float4*)a.src[s])[v];
    ushort4 o; o.x=f2bf(x.x); o.y=f2bf(x.y); o.z=f2bf(x.z); o.w=f2bf(x.w);
    ((ushort4*)a.dst[s])[v] = o;
  }
}

// ---------------- transpose the attention V-weight block: vt[l][k][j] = aiw[l][2DM+j][k] --
__global__ __launch_bounds__(256) void transv_kernel(const float* __restrict__ aiw,
    ushort* __restrict__ vt){
  __shared__ float t[32][33];
  const int l = blockIdx.z;
  const int j0 = blockIdx.x*32, k0 = blockIdx.y*32;
  const int tx = threadIdx.x & 31, ty = threadIdx.x >> 5;  // ty 0..7
  const float* src = aiw + (size_t)l*3*DM*DM + (size_t)(2*DM)*DM;
  #pragma unroll
  for (int i=0;i<4;i++){
    int j = ty + i*8;
    t[j][tx] = src[(size_t)(j0+j)*DM + k0+tx];
  }
  __syncthreads();
  ushort* dst = vt + (size_t)l*DM*DM;
  #pragma unroll
  for (int i=0;i<4;i++){
    int k = ty + i*8;
    dst[(size_t)(k0+k)*DM + j0+tx] = f2bf(t[tx][k]);
  }
}

// ---------------- combined attention bias: bc[l][i] = bo[i] + sum_j Wo[i][j]*bv[j] -------
__global__ __launch_bounds__(256) void bcomb_kernel(const float* __restrict__ aow,
    const float* __restrict__ aib, const float* __restrict__ aob, float* __restrict__ bc){
  const int l = blockIdx.x, i = threadIdx.x;
  const float* wo = aow + (size_t)l*DM*DM + (size_t)i*DM;
  const float* bv = aib + (size_t)l*3*DM + 2*DM;
  float acc = aob[(size_t)l*DM + i];
  for (int j=0;j<DM;j++) acc = fmaf(wo[j], bv[j], acc);
  bc[l*DM+i] = acc;
}

// ---------------- embedding gather ----------------
__global__ __launch_bounds__(256) void embed_kernel(const int* __restrict__ tok,
    const float* __restrict__ emb, float* __restrict__ x){
  int row = blockIdx.x;
  int c = threadIdx.x;
  x[(size_t)row*DM + c] = emb[(size_t)tok[row]*DM + c];
}

// ---------------- layernorm: one wave per row of 256; writes bf16 ----------------
__global__ __launch_bounds__(64) void ln_kernel(const float* __restrict__ x,
    const float* __restrict__ g, const float* __restrict__ b, ushort* __restrict__ o){
  int row = blockIdx.x;
  int lane = threadIdx.x;
  const float4 v = *(const float4*)(x + (size_t)row*DM + lane*4);
  float s = v.x+v.y+v.z+v.w;
  #pragma unroll
  for (int off=32; off; off>>=1) s += __shfl_xor(s, off, 64);
  float m = s * (1.f/DM);
  float d0=v.x-m, d1=v.y-m, d2=v.z-m, d3=v.w-m;
  float q = d0*d0+d1*d1+d2*d2+d3*d3;
  #pragma unroll
  for (int off=32; off; off>>=1) q += __shfl_xor(q, off, 64);
  float r = rsqrtf(q*(1.f/DM) + 1e-5f);
  const float4 gv = *(const float4*)(g + lane*4);
  const float4 bv = *(const float4*)(b + lane*4);
  ushort4 ov;
  ov.x = f2bf(d0*r*gv.x + bv.x);
  ov.y = f2bf(d1*r*gv.y + bv.y);
  ov.z = f2bf(d2*r*gv.z + bv.z);
  ov.w = f2bf(d3*r*gv.w + bv.w);
  *(ushort4*)(o + (size_t)row*DM + lane*4) = ov;
}

// ---------------- 64x64 MFMA bf16 NT GEMM (4 waves, BK=32), optional z-batched ----------
template<bool BIAS, bool RES, bool OUTF32, bool OUTBF>
__global__ __launch_bounds__(256) void mgemm(
    const ushort* __restrict__ A, int lda,
    const ushort* __restrict__ W,
    const float* __restrict__ bias,
    const float* __restrict__ res,
    float* __restrict__ Df, ushort* __restrict__ Db,
    int N, int K, size_t zsA, size_t zsW, size_t zsD)
{
  __shared__ ushort As[64*40];
  __shared__ ushort Bs[64*40];
  A += blockIdx.z*zsA; W += blockIdx.z*zsW;
  const int tid = threadIdx.x;
  const int bm = blockIdx.x*64, bn = blockIdx.y*64;
  const int r = tid>>2, c = tid&3;
  const int lane = tid & 63, wave = tid>>6;
  const int wm = wave>>1, wn = wave&1;
  const int lr = lane&15, lk = (lane>>4)*8;
  f32x4 acc[2][2] = {};
  for (int k0=0; k0<K; k0+=32){
    uint4 av = *(const uint4*)(A + (size_t)(bm+r)*lda + k0 + c*8);
    uint4 wv = make_uint4(0,0,0,0);
    const int n = bn + r;
    if (n < N) wv = *(const uint4*)(W + (size_t)n*K + k0 + c*8);
    __syncthreads();
    *(uint4*)&As[r*40 + c*8] = av;
    *(uint4*)&Bs[r*40 + c*8] = wv;
    __syncthreads();
    short8 a0 = *(const short8*)&As[(wm*32 +  0 + lr)*40 + lk];
    short8 a1 = *(const short8*)&As[(wm*32 + 16 + lr)*40 + lk];
    short8 b0 = *(const short8*)&Bs[(wn*32 +  0 + lr)*40 + lk];
    short8 b1 = *(const short8*)&Bs[(wn*32 + 16 + lr)*40 + lk];
    acc[0][0] = __builtin_amdgcn_mfma_f32_16x16x32_bf16(a0,b0,acc[0][0],0,0,0);
    acc[0][1] = __builtin_amdgcn_mfma_f32_16x16x32_bf16(a0,b1,acc[0][1],0,0,0);
    acc[1][0] = __builtin_amdgcn_mfma_f32_16x16x32_bf16(a1,b0,acc[1][0],0,0,0);
    acc[1][1] = __builtin_amdgcn_mfma_f32_16x16x32_bf16(a1,b1,acc[1][1],0,0,0);
  }
  #pragma unroll
  for (int i=0;i<2;i++){
    #pragma unroll
    for (int j=0;j<2;j++){
      #pragma unroll
      for (int q=0;q<4;q++){
        const int row = bm + wm*32 + i*16 + (lane>>4)*4 + q;
        const int col = bn + wn*32 + j*16 + lr;
        if (col < N){
          float v = acc[i][j][q];
          if (BIAS) v += bias[col];
          if (RES)  v += res[(size_t)row*N + col];
          if (OUTF32) Df[blockIdx.z*zsD + (size_t)row*N + col] = v;
          if (OUTBF)  Db[blockIdx.z*zsD + (size_t)row*N + col] = f2bf(v);
        }
      }
    }
  }
}

// ---------------- 128x128 MFMA bf16 NT GEMM (8 waves, BK=32) ----------------
template<bool BIAS, bool OUTF32, bool OUTBF>
__global__ __launch_bounds__(512) void gemm128(
    const ushort* __restrict__ A, int lda,
    const ushort* __restrict__ W,
    const float* __restrict__ bias,
    float* __restrict__ Df, ushort* __restrict__ Db,
    int N, int K)
{
  __shared__ ushort As[128*40];
  __shared__ ushort Bs[128*40];
  const int tid = threadIdx.x;
  const int bm = blockIdx.x*128, bn = blockIdx.y*128;
  const int r = tid>>2, c = tid&3;
  const int lane = tid & 63, wave = tid>>6;
  const int wm = wave>>2, wn = wave&3;       // 2 x 4 waves
  const int lr = lane&15, lk = (lane>>4)*8;
  f32x4 acc[4][2] = {};
  for (int k0=0; k0<K; k0+=32){
    uint4 av = *(const uint4*)(A + (size_t)(bm+r)*lda + k0 + c*8);
    uint4 wv = make_uint4(0,0,0,0);
    const int n = bn + r;
    if (n < N) wv = *(const uint4*)(W + (size_t)n*K + k0 + c*8);
    __syncthreads();
    *(uint4*)&As[r*40 + c*8] = av;
    *(uint4*)&Bs[r*40 + c*8] = wv;
    __syncthreads();
    short8 af[4], bfr[2];
    #pragma unroll
    for (int i=0;i<4;i++) af[i] = *(const short8*)&As[(wm*64 + i*16 + lr)*40 + lk];
    #pragma unroll
    for (int j=0;j<2;j++) bfr[j] = *(const short8*)&Bs[(wn*32 + j*16 + lr)*40 + lk];
    #pragma unroll
    for (int i=0;i<4;i++)
      #pragma unroll
      for (int j=0;j<2;j++)
        acc[i][j] = __builtin_amdgcn_mfma_f32_16x16x32_bf16(af[i],bfr[j],acc[i][j],0,0,0);
  }
  #pragma unroll
  for (int i=0;i<4;i++){
    #pragma unroll
    for (int j=0;j<2;j++){
      #pragma unroll
      for (int q=0;q<4;q++){
        const int row = bm + wm*64 + i*16 + (lane>>4)*4 + q;
        const int col = bn + wn*32 + j*16 + lr;
        if (col < N){
          float v = acc[i][j][q];
          if (BIAS) v += bias[col];
          if (OUTF32) Df[(size_t)row*N + col] = v;
          if (OUTBF)  Db[(size_t)row*N + col] = f2bf(v);
        }
      }
    }
  }
}

// ---------------- depthwise causal conv (DC=4) + SiLU: bf16 in, bf16 out, x4 vector ------
__global__ __launch_bounds__(256) void conv_silu_kernel(const ushort* __restrict__ xz,
    const float* __restrict__ cw, const float* __restrict__ cb, ushort* __restrict__ ub){
  int idx = blockIdx.x*256 + threadIdx.x;   // over 2048*128
  int dq = idx & 127;
  int row = idx >> 7;
  int t = row & (SL-1);
  int d4 = dq*4;
  const ushort* base = xz + (size_t)row*(2*DI) + d4;
  ushort4 zz = make_ushort4(0,0,0,0);
  ushort4 x0 = *(const ushort4*)base;
  ushort4 x1 = (t>=1) ? *(const ushort4*)(base - (2*DI))   : zz;
  ushort4 x2 = (t>=2) ? *(const ushort4*)(base - 2*(2*DI)) : zz;
  ushort4 x3 = (t>=3) ? *(const ushort4*)(base - 3*(2*DI)) : zz;
  float a0[4]={bf2f(x0.x),bf2f(x0.y),bf2f(x0.z),bf2f(x0.w)};
  float a1[4]={bf2f(x1.x),bf2f(x1.y),bf2f(x1.z),bf2f(x1.w)};
  float a2[4]={bf2f(x2.x),bf2f(x2.y),bf2f(x2.z),bf2f(x2.w)};
  float a3[4]={bf2f(x3.x),bf2f(x3.y),bf2f(x3.z),bf2f(x3.w)};
  const float4 cbv = *(const float4*)(cb + d4);
  float cbr[4]={cbv.x,cbv.y,cbv.z,cbv.w};
  ushort o[4];
  #pragma unroll
  for (int i=0;i<4;i++){
    const float4 w = *(const float4*)(cw + (size_t)(d4+i)*4);
    float acc = cbr[i];
    acc = fmaf(a3[i], w.x, acc);
    acc = fmaf(a2[i], w.y, acc);
    acc = fmaf(a1[i], w.z, acc);
    acc = fmaf(a0[i], w.w, acc);
    o[i] = f2bf(acc * sigm(acc));
  }
  ushort4 ov; ov.x=o[0]; ov.y=o[1]; ov.z=o[2]; ov.w=o[3];
  *(ushort4*)(ub + (size_t)row*DI + d4) = ov;
}

// ---------------- selective scan: lane = (d,s); 16 states across 16 lanes ----------------
// grid (BB, DI/16), block 256 = 16 d-channels x 16 states. Fused dt-proj+softplus+gate.
__global__ __launch_bounds__(256) void scan_kernel(
    const float* __restrict__ xdbl,  // [2048][48] fp32
    const ushort* __restrict__ ub,   // [2048][512] bf16
    const ushort* __restrict__ xzb,  // [2048][1024] bf16 (z at +512)
    const float* __restrict__ dtw,   // [512][16]
    const float* __restrict__ dtb,   // [512]
    const float* __restrict__ alog,  // [512][16]
    const float* __restrict__ Dp,    // [512]
    ushort* __restrict__ ymb)        // [2048][512] bf16
{
  __shared__ float xs[SL][48];
  const int b = blockIdx.x;
  const int tid = threadIdx.x;
  const int s = tid & 15;
  const int d = blockIdx.y*16 + (tid>>4);
  for (int i=tid; i<SL*48/4; i+=256)
    ((float4*)&xs[0][0])[i] = ((const float4*)(xdbl + (size_t)b*SL*48))[i];
  const float wdt = dtw[(size_t)d*DTR + s];
  const float As = -__expf(alog[(size_t)d*DS_ + s]);
  const float bdt = dtb[d], Dv = Dp[d];
  float h = 0.f;
  __syncthreads();
  for (int t=0;t<SL;t++){
    const int row = b*SL + t;
    const float uv = bf2f(ub[(size_t)row*DI + d]);
    float p = xs[t][s]*wdt;
    p += __shfl_xor(p,1,16); p += __shfl_xor(p,2,16);
    p += __shfl_xor(p,4,16); p += __shfl_xor(p,8,16);
    float dtv = p + bdt;
    dtv = (dtv > 20.f) ? dtv : __logf(1.f + __expf(dtv));
    h = fmaf(h, __expf(dtv*As), dtv*uv*xs[t][16+s]);
    float q = h*xs[t][32+s];
    q += __shfl_xor(q,1,16); q += __shfl_xor(q,2,16);
    q += __shfl_xor(q,4,16); q += __shfl_xor(q,8,16);
    if (s == 0){
      const float zv = bf2f(xzb[(size_t)row*(2*DI) + DI + d]);
      const float sz = zv * sigm(zv);
      ymb[(size_t)row*DI + d] = f2bf((q + uv*Dv)*sz);
    }
  }
}

extern "C" void kernel_launch(void* const* d_in, const int* in_sizes, int n_in,
                              void* d_out, int out_size, void* d_ws, size_t ws_size,
                              hipStream_t stream){
  const int*   tokens = (const int*)d_in[0];
  const float* emb    = (const float*)d_in[1];
  const float* head_b = (const float*)d_in[2];
  const float* in_w   = (const float*)d_in[3];
  const float* conv_w = (const float*)d_in[4];
  const float* conv_b = (const float*)d_in[5];
  const float* xp_w   = (const float*)d_in[6];
  const float* dt_w   = (const float*)d_in[7];
  const float* dt_b   = (const float*)d_in[8];
  const float* a_log  = (const float*)d_in[9];
  const float* d_par  = (const float*)d_in[10];
  const float* out_w  = (const float*)d_in[11];
  const float* ai_w   = (const float*)d_in[12];
  const float* ai_b   = (const float*)d_in[13];
  const float* ao_w   = (const float*)d_in[14];
  const float* ao_b   = (const float*)d_in[15];
  const float* ln1g   = (const float*)d_in[16];
  const float* ln1b   = (const float*)d_in[17];
  const float* ln2g   = (const float*)d_in[18];
  const float* ln2b   = (const float*)d_in[19];
  const float* lnfg   = (const float*)d_in[20];
  const float* lnfb   = (const float*)d_in[21];
  float* out = (float*)d_out;

  // ---- workspace layout ----
  float* fp = (float*)d_ws;
  float* x     = fp;  fp += M_TOK*DM;     // fp32 residual
  float* xdbl  = fp;  fp += M_TOK*48;
  float* bcomb = fp;  fp += NL*DM;
  fp += (16 - (((size_t)(fp - (float*)d_ws)) & 15)) & 15;   // keep 16B-ish alignment
  ushort* up = (ushort*)fp;
  ushort* xn_bf  = up;  up += M_TOK*DM;
  ushort* xz_bf  = up;  up += M_TOK*2*DI;
  ushort* u_bf   = up;  up += M_TOK*DI;
  ushort* ym_bf  = up;  up += M_TOK*DI;
  ushort* emb_bf = up;  up += VOCAB*DM;
  ushort* inw_bf = up;  up += NL*2*DI*DM;
  ushort* outw_bf= up;  up += NL*DM*DI;
  ushort* xpw_bf = up;  up += NL*48*DI;
  ushort* aow_bf = up;  up += NL*DM*DM;
  ushort* vt_bf  = up;  up += NL*DM*DM;
  ushort* wvo_bf = up;  up += NL*DM*DM;

  // ---- weight conversion (one launch) ----
  CvtArgs ca;
  const float* srcs[5] = {emb, in_w, out_w, xp_w, ao_w};
  ushort* dsts[5] = {emb_bf, inw_bf, outw_bf, xpw_bf, aow_bf};
  const int cnts[5] = {VOCAB*DM, NL*2*DI*DM, NL*DM*DI, NL*48*DI, NL*DM*DM};
  int cum = 0;
  ca.cum[0] = 0;
  for (int i=0;i<5;i++){
    ca.src[i]=srcs[i]; ca.dst[i]=dsts[i]; ca.nvec[i]=cnts[i]/4;
    cum += (ca.nvec[i] + 255)/256;
    ca.cum[i+1] = cum;
  }
  convert_kernel<<<cum,256,0,stream>>>(ca);
  transv_kernel<<<dim3(8,8,NL),256,0,stream>>>(ai_w, vt_bf);
  // Wvo[l] = Wo @ Wv  (bf16, batched over layers)
  mgemm<false,false,false,true><<<dim3(4,4,NL),256,0,stream>>>(
      aow_bf, DM, vt_bf, nullptr, nullptr, nullptr, wvo_bf, DM, DM,
      (size_t)DM*DM, (size_t)DM*DM, (size_t)DM*DM);
  bcomb_kernel<<<NL,256,0,stream>>>(ao_w, ai_b, ao_b, bcomb);

  embed_kernel<<<M_TOK,256,0,stream>>>(tokens, emb, x);
  for (int l=0;l<NL;l++){
    // --- mamba branch ---
    ln_kernel<<<M_TOK,64,0,stream>>>(x, ln1g+l*DM, ln1b+l*DM, xn_bf);
    gemm128<false,false,true><<<dim3(M_TOK/128,(2*DI)/128),512,0,stream>>>(
        xn_bf, DM, inw_bf + (size_t)l*2*DI*DM, nullptr, nullptr, xz_bf, 2*DI, DM);
    conv_silu_kernel<<<(M_TOK*DI/4)/256,256,0,stream>>>(
        xz_bf, conv_w + (size_t)l*DI*4, conv_b + (size_t)l*DI, u_bf);
    mgemm<false,false,true,false><<<dim3(M_TOK/64,1),256,0,stream>>>(
        u_bf, DI, xpw_bf + (size_t)l*48*DI, nullptr, nullptr, xdbl, nullptr, 48, DI, 0,0,0);
    scan_kernel<<<dim3(BB,DI/16),256,0,stream>>>(
        xdbl, u_bf, xz_bf, dt_w + (size_t)l*DI*DTR, dt_b + (size_t)l*DI,
        a_log + (size_t)l*DI*DS_, d_par + (size_t)l*DI, ym_bf);
    mgemm<false,true,true,false><<<dim3(M_TOK/64,DM/64),256,0,stream>>>(
        ym_bf, DI, outw_bf + (size_t)l*DM*DI, nullptr, x, x, nullptr, DM, DI, 0,0,0);
    // --- attention branch (collapsed + algebraically fused: x += ln2(x) @ Wvo^T + bc) ---
    ln_kernel<<<M_TOK,64,0,stream>>>(x, ln2g+l*DM, ln2b+l*DM, xn_bf);
    mgemm<true,true,true,false><<<dim3(M_TOK/64,DM/64),256,0,stream>>>(
        xn_bf, DM, wvo_bf + (size_t)l*DM*DM, bcomb + l*DM, x, x, nullptr, DM, DM, 0,0,0);
  }
  // --- final LN + tied head ---
  ln_kernel<<<M_TOK,64,0,stream>>>(x, lnfg, lnfb, xn_bf);
  gemm128<true,true,false><<<dim3(M_TOK/128,(VOCAB+127)/128),512,0,stream>>>(
      xn_bf, DM, emb_bf, head_b, out, nullptr, VOCAB, DM);
}